// Round 3
// baseline (3760.786 us; speedup 1.0000x reference)
//
#include <hip/hip_runtime.h>
#include <hip/hip_bf16.h>

#define NATOMS 10000
#define NEDGES 320000
#define H 128
#define NRBF 50
#define NELEM (NATOMS * H)

typedef unsigned short u16;
typedef unsigned int u32;

__device__ __forceinline__ float bfu(u16 u) { return __uint_as_float(((u32)u) << 16); }
// dtype-flexible load: bf==1 -> buffer holds bf16, else fp32
__device__ __forceinline__ float ldf(const void* p, int i, int bf) {
    return bf ? bfu(((const u16*)p)[i]) : ((const float*)p)[i];
}
__device__ __forceinline__ float silu_f(float v) { return v / (1.f + __expf(-v)); }

// ---- dtype detect: means[49]==1.0 by construction. bf16 packing puts 0x3F80
// in the high half of u32 word 24; fp32 word 24 is bits of ~0.493 (0x3EFC...).
__global__ void k_detect(const void* means, int* flag) {
    if (threadIdx.x == 0) {
        u32 w = ((const u32*)means)[24];
        *flag = ((w >> 16) == 0x3F80u) ? 1 : 0;
    }
}

// ---- embed: x0[n,f] = emb[z[n],f]
__global__ __launch_bounds__(256) void k_embed(const int* __restrict__ z, const void* emb,
                                               float* __restrict__ x0, const int* flagp) {
    int bf = *flagp;
    int i = blockIdx.x * 256 + threadIdx.x;
    if (i < NELEM) {
        int n = i >> 7, f = i & 127;
        x0[i] = ldf(emb, z[n] * H + f, bf);
    }
}

// ---- output: fp32 state -> d_out in detected dtype
__global__ __launch_bounds__(256) void k_store(const float* __restrict__ x, void* out,
                                               const int* flagp) {
    int bf = *flagp;
    int i = blockIdx.x * 256 + threadIdx.x;
    if (i < NELEM) {
        float v = x[i];
        if (bf) {
            u32 u = __float_as_uint(v);
            ((u16*)out)[i] = (u16)((u + 0x7FFFu + ((u >> 16) & 1u)) >> 16);  // RNE
        } else {
            ((float*)out)[i] = v;
        }
    }
}

// ---- node GEMM, K=128: out[n,f] = op(sum_k in[n,k]*W[woff + f*wstride + k] + b[f])
// mode 0 write, 1 silu, 2 accumulate(residual)
__global__ __launch_bounds__(1024) void k_node_gemm(const float* __restrict__ in,
                                                    const void* W, int woff, int wstride,
                                                    const void* bias, float* __restrict__ out,
                                                    int mode, const int* flagp) {
    __shared__ __align__(16) float sW[H * 132];
    __shared__ __align__(16) float sIn[16][132];
    __shared__ float sB[H];
    int tid = threadIdx.x;
    int bf = *flagp;
    for (int i = tid; i < H * H; i += 1024) {
        int f2 = i >> 7, k = i & 127;
        sW[f2 * 132 + k] = ldf(W, woff + f2 * wstride + k, bf);
    }
    if (tid < H) sB[tid] = bias ? ldf(bias, tid, bf) : 0.f;
    __syncthreads();
    int g = tid >> 7, f = tid & 127;
    for (int base = blockIdx.x * 16; base < NATOMS; base += gridDim.x * 16) {
        int n0 = base + 2 * g, n1 = n0 + 1;   // NATOMS % 16 == 0 -> always in range
        sIn[2 * g][f] = in[n0 * H + f];
        sIn[2 * g + 1][f] = in[n1 * H + f];
        __syncthreads();
        float a0 = 0.f, a1 = 0.f;
        #pragma unroll
        for (int k = 0; k < H; k += 4) {
            float4 w4 = *(const float4*)&sW[f * 132 + k];
            float4 i0 = *(const float4*)&sIn[2 * g][k];
            float4 i1 = *(const float4*)&sIn[2 * g + 1][k];
            a0 = fmaf(w4.x, i0.x, a0); a0 = fmaf(w4.y, i0.y, a0);
            a0 = fmaf(w4.z, i0.z, a0); a0 = fmaf(w4.w, i0.w, a0);
            a1 = fmaf(w4.x, i1.x, a1); a1 = fmaf(w4.y, i1.y, a1);
            a1 = fmaf(w4.z, i1.z, a1); a1 = fmaf(w4.w, i1.w, a1);
        }
        float v0 = a0 + sB[f], v1 = a1 + sB[f];
        if (mode == 1) { v0 = silu_f(v0); v1 = silu_f(v1); }
        if (mode == 2) { out[n0 * H + f] += v0; out[n1 * H + f] += v1; }
        else           { out[n0 * H + f] = v0;  out[n1 * H + f] = v1; }
        __syncthreads();
    }
}

// ---- RBF helper: writes sEA row (C*rbf) and sC for one edge; lanes k<50 active
__device__ __forceinline__ void rbf_row(const void* ew, int e, int k, int bf,
                                        const float* sM, const float* sBe,
                                        float* eaRow, float* cSlot) {
    float w = ldf(ew, e, bf);
    float c = 0.5f * (__cosf(w * 0.62831853072f) + 1.f);
    if (!(w < 5.f)) c = 0.f;
    float t = __expf(-w) - sM[k];
    eaRow[k] = c * __expf(-sBe[k] * t * t);
    if (k == 0) *cSlot = c;
}

// ---- NeighborEmbedding edges: W=(EA@pw.T+pb)*C, mask src!=dst; agg[src]+=W*x0[dst]
__global__ __launch_bounds__(1024) void k_ne_edge(const int* __restrict__ src,
                                                  const int* __restrict__ dst,
                                                  const void* ew, const void* means,
                                                  const void* betas, const void* pw,
                                                  const void* pb, const float* __restrict__ x0,
                                                  float* __restrict__ agg, const int* flagp) {
    __shared__ __align__(16) float sW[H * 52];
    __shared__ __align__(16) float sEA[16][52];
    __shared__ float sB[H], sM[NRBF], sBe[NRBF], sC[16];
    int tid = threadIdx.x;
    int bf = *flagp;
    for (int i = tid; i < H * NRBF; i += 1024) {
        int f2 = i / NRBF, k = i - f2 * NRBF;
        sW[f2 * 52 + k] = ldf(pw, i, bf);
    }
    if (tid < 2 * H) sW[(tid >> 1) * 52 + 50 + (tid & 1)] = 0.f;   // zero pads
    if (tid < H) sB[tid] = ldf(pb, tid, bf);
    if (tid < NRBF) { sM[tid] = ldf(means, tid, bf); sBe[tid] = ldf(betas, tid, bf); }
    if (tid < 32) sEA[tid >> 1][50 + (tid & 1)] = 0.f;
    __syncthreads();
    int g = tid >> 7, f = tid & 127;
    for (int base = blockIdx.x * 16; base < NEDGES; base += gridDim.x * 16) {
        int e0 = base + 2 * g, e1 = e0 + 1;  // NEDGES % 16 == 0 -> in range
        if (f < NRBF)                rbf_row(ew, e0, f,      bf, sM, sBe, sEA[2 * g],     &sC[2 * g]);
        else if (f >= 64 && f < 64 + NRBF) rbf_row(ew, e1, f - 64, bf, sM, sBe, sEA[2 * g + 1], &sC[2 * g + 1]);
        __syncthreads();
        float a0 = 0.f, a1 = 0.f;
        #pragma unroll
        for (int k = 0; k < 52; k += 4) {
            float4 w4 = *(const float4*)&sW[f * 52 + k];
            float4 e0v = *(const float4*)&sEA[2 * g][k];
            float4 e1v = *(const float4*)&sEA[2 * g + 1][k];
            a0 = fmaf(w4.x, e0v.x, a0); a0 = fmaf(w4.y, e0v.y, a0);
            a0 = fmaf(w4.z, e0v.z, a0); a0 = fmaf(w4.w, e0v.w, a0);
            a1 = fmaf(w4.x, e1v.x, a1); a1 = fmaf(w4.y, e1v.y, a1);
            a1 = fmaf(w4.z, e1v.z, a1); a1 = fmaf(w4.w, e1v.w, a1);
        }
        int s0 = src[e0], d0 = dst[e0], s1 = src[e1], d1 = dst[e1];
        if (s0 != d0) atomicAdd(&agg[s0 * H + f], (a0 + sB[f]) * sC[2 * g]     * x0[d0 * H + f]);
        if (s1 != d1) atomicAdd(&agg[s1 * H + f], (a1 + sB[f]) * sC[2 * g + 1] * x0[d1 * H + f]);
        __syncthreads();
    }
}

// ---- interaction edges: Wf=(silu(EA@w0.T+b0)@w1.T+b1)*C; a[src]+=Wf*h[dst]
__global__ __launch_bounds__(1024) void k_edge_filter(const int* __restrict__ src,
                                                      const int* __restrict__ dst,
                                                      const void* ew, const void* means,
                                                      const void* betas,
                                                      const void* w0, int w0off,
                                                      const void* b0, int b0off,
                                                      const void* w1, int w1off,
                                                      const void* b1, int b1off,
                                                      const float* __restrict__ h,
                                                      float* __restrict__ a,
                                                      const int* flagp) {
    __shared__ __align__(16) float sW0[H * 52];
    __shared__ __align__(16) float sW1[H * 132];
    __shared__ __align__(16) float sT[16][132];
    __shared__ __align__(16) float sEA[16][52];
    __shared__ float sB0[H], sB1[H], sM[NRBF], sBe[NRBF], sC[16];
    int tid = threadIdx.x;
    int bf = *flagp;
    for (int i = tid; i < H * NRBF; i += 1024) {
        int f2 = i / NRBF, k = i - f2 * NRBF;
        sW0[f2 * 52 + k] = ldf(w0, w0off + i, bf);
    }
    if (tid < 2 * H) sW0[(tid >> 1) * 52 + 50 + (tid & 1)] = 0.f;
    for (int i = tid; i < H * H; i += 1024) {
        int f2 = i >> 7, k = i & 127;
        sW1[f2 * 132 + k] = ldf(w1, w1off + i, bf);
    }
    if (tid < H) { sB0[tid] = ldf(b0, b0off + tid, bf); sB1[tid] = ldf(b1, b1off + tid, bf); }
    if (tid < NRBF) { sM[tid] = ldf(means, tid, bf); sBe[tid] = ldf(betas, tid, bf); }
    if (tid < 32) sEA[tid >> 1][50 + (tid & 1)] = 0.f;
    __syncthreads();
    int g = tid >> 7, f = tid & 127;
    for (int base = blockIdx.x * 16; base < NEDGES; base += gridDim.x * 16) {
        int e0 = base + 2 * g, e1 = e0 + 1;
        if (f < NRBF)                rbf_row(ew, e0, f,      bf, sM, sBe, sEA[2 * g],     &sC[2 * g]);
        else if (f >= 64 && f < 64 + NRBF) rbf_row(ew, e1, f - 64, bf, sM, sBe, sEA[2 * g + 1], &sC[2 * g + 1]);
        __syncthreads();
        // phase 1: t = silu(EA @ w0.T + b0)
        float a0 = 0.f, a1 = 0.f;
        #pragma unroll
        for (int k = 0; k < 52; k += 4) {
            float4 w4 = *(const float4*)&sW0[f * 52 + k];
            float4 e0v = *(const float4*)&sEA[2 * g][k];
            float4 e1v = *(const float4*)&sEA[2 * g + 1][k];
            a0 = fmaf(w4.x, e0v.x, a0); a0 = fmaf(w4.y, e0v.y, a0);
            a0 = fmaf(w4.z, e0v.z, a0); a0 = fmaf(w4.w, e0v.w, a0);
            a1 = fmaf(w4.x, e1v.x, a1); a1 = fmaf(w4.y, e1v.y, a1);
            a1 = fmaf(w4.z, e1v.z, a1); a1 = fmaf(w4.w, e1v.w, a1);
        }
        sT[2 * g][f] = silu_f(a0 + sB0[f]);
        sT[2 * g + 1][f] = silu_f(a1 + sB0[f]);
        __syncthreads();
        // phase 2: Wf = (t @ w1.T + b1) * C, scatter
        float c0 = 0.f, c1 = 0.f;
        #pragma unroll
        for (int k = 0; k < H; k += 4) {
            float4 w4 = *(const float4*)&sW1[f * 132 + k];
            float4 t0 = *(const float4*)&sT[2 * g][k];
            float4 t1 = *(const float4*)&sT[2 * g + 1][k];
            c0 = fmaf(w4.x, t0.x, c0); c0 = fmaf(w4.y, t0.y, c0);
            c0 = fmaf(w4.z, t0.z, c0); c0 = fmaf(w4.w, t0.w, c0);
            c1 = fmaf(w4.x, t1.x, c1); c1 = fmaf(w4.y, t1.y, c1);
            c1 = fmaf(w4.z, t1.z, c1); c1 = fmaf(w4.w, t1.w, c1);
        }
        int s0 = src[e0], d0 = dst[e0], s1 = src[e1], d1 = dst[e1];
        atomicAdd(&a[s0 * H + f], (c0 + sB1[f]) * sC[2 * g]     * h[d0 * H + f]);
        atomicAdd(&a[s1 * H + f], (c1 + sB1[f]) * sC[2 * g + 1] * h[d1 * H + f]);
        __syncthreads();
    }
}

extern "C" void kernel_launch(void* const* d_in, const int* in_sizes, int n_in,
                              void* d_out, int out_size, void* d_ws, size_t ws_size,
                              hipStream_t stream) {
    const int* z  = (const int*)d_in[0];
    const int* ei = (const int*)d_in[1];
    const void* ew        = d_in[2];
    const void* emb       = d_in[3];
    const void* means     = d_in[4];
    const void* betas     = d_in[5];
    const void* ne_proj_w = d_in[6];
    const void* ne_proj_b = d_in[7];
    const void* ne_comb_w = d_in[8];
    const void* ne_comb_b = d_in[9];
    const void* mlp_w0    = d_in[10];
    const void* mlp_b0    = d_in[11];
    const void* mlp_w1    = d_in[12];
    const void* mlp_b1    = d_in[13];
    const void* lin1_w    = d_in[14];
    const void* lin2_w    = d_in[15];
    const void* lin2_b    = d_in[16];
    const void* lin_w     = d_in[17];
    const void* lin_b     = d_in[18];

    const int* srcp = ei;
    const int* dstp = ei + NEDGES;

    float* buf0 = (float*)d_ws;          // x0, then h
    float* buf1 = buf0 + NELEM;          // scatter accumulator
    float* x    = buf1 + NELEM;          // persistent fp32 node state
    int*   flag = (int*)(x + NELEM);

    const int gElem = (NELEM + 255) / 256;

    k_detect<<<1, 64, 0, stream>>>(means, flag);
    k_embed<<<gElem, 256, 0, stream>>>(z, emb, buf0, flag);

    // NeighborEmbedding
    hipMemsetAsync(buf1, 0, (size_t)NELEM * sizeof(float), stream);
    k_ne_edge<<<512, 1024, 0, stream>>>(srcp, dstp, ew, means, betas,
                                        ne_proj_w, ne_proj_b, buf0, buf1, flag);
    k_node_gemm<<<512, 1024, 0, stream>>>(buf0, ne_comb_w, 0,   256, ne_comb_b, x, 0, flag);
    k_node_gemm<<<512, 1024, 0, stream>>>(buf1, ne_comb_w, 128, 256, nullptr,   x, 2, flag);

    for (int L = 0; L < 3; ++L) {
        k_node_gemm<<<512, 1024, 0, stream>>>(x, lin1_w, L * H * H, 128, nullptr, buf0, 0, flag);
        hipMemsetAsync(buf1, 0, (size_t)NELEM * sizeof(float), stream);
        k_edge_filter<<<256, 1024, 0, stream>>>(srcp, dstp, ew, means, betas,
                                                mlp_w0, L * H * NRBF, mlp_b0, L * H,
                                                mlp_w1, L * H * H,    mlp_b1, L * H,
                                                buf0, buf1, flag);
        k_node_gemm<<<512, 1024, 0, stream>>>(buf1, lin2_w, L * H * H, 128, lin2_b, buf0, 1, flag);
        k_node_gemm<<<512, 1024, 0, stream>>>(buf0, lin_w,  L * H * H, 128, lin_b,  x,    2, flag);
    }

    k_store<<<gElem, 256, 0, stream>>>(x, d_out, flag);
}